// Round 18
// baseline (195.866 us; speedup 1.0000x reference)
//
#include <hip/hip_runtime.h>

// Problem constants (B=8, T=4096, D=1024, C=64, P=512)
// Outputs FLOAT32, concatenated: pattern_emb, assignments, logits, hard_indices, Q
#define O_PE 0
#define O_AS 33554432
#define O_LG 50331648
#define O_HI 67108864
#define O_Q  67141632

typedef float vf4 __attribute__((ext_vector_type(4)));  // native vector for NT builtins

__device__ __forceinline__ void nts4(float* p, float4 v) {
  vf4 t; t.x = v.x; t.y = v.y; t.z = v.z; t.w = v.w;
  __builtin_nontemporal_store(t, (vf4*)p);
}
__device__ __forceinline__ float4 ntl4(const float* p) {
  vf4 t = __builtin_nontemporal_load((const vf4*)p);
  float4 r; r.x = t.x; r.y = t.y; r.z = t.z; r.w = t.w;
  return r;
}

// ---------------------------------------------------------------------------
// K0: precompute  (grid = 512 blocks, one per pattern)
// ---------------------------------------------------------------------------
__global__ void k0_pre(const float* __restrict__ patterns, const float* __restrict__ w2,
                       const float* __restrict__ b2, const float* __restrict__ ln2g,
                       const float* __restrict__ ln2b, const int* __restrict__ epoch,
                       const int* __restrict__ total_epochs,
                       float* __restrict__ invt, float* __restrict__ knT,
                       float* __restrict__ peb) {
  const int b = blockIdx.x, t = threadIdx.x;
  __shared__ float pat[64];
  __shared__ float red[8];

  if (b == 0 && t == 0) {
    float ep = (float)epoch[0], te = (float)total_epochs[0];
    float warm = te * 0.1f;
    float temp;
    if (ep < warm) temp = 2.0f;
    else {
      float prog = (ep - warm) / (te - warm);
      temp = fmaxf(0.7f, 2.0f - 1.3f * prog);
    }
    invt[0] = 1.0f / temp;
  }

  if (t < 64) pat[t] = patterns[b * 64 + t];
  __syncthreads();

  if (t < 64) {
    float v = pat[t];
    float s = v * v;
    #pragma unroll
    for (int m = 1; m < 64; m <<= 1) s += __shfl_xor(s, m);
    float scale = 1.0f / fmaxf(sqrtf(s), 1e-12f);
    knT[(size_t)t * 512 + b] = v * scale;
  }

  const int d0 = t * 4;
  float4 acc = *(const float4*)&b2[d0];
  #pragma unroll 8
  for (int k = 0; k < 64; ++k) {
    float pk = pat[k];
    float4 w = *(const float4*)&w2[(size_t)k * 1024 + d0];
    acc.x = fmaf(pk, w.x, acc.x);
    acc.y = fmaf(pk, w.y, acc.y);
    acc.z = fmaf(pk, w.z, acc.z);
    acc.w = fmaf(pk, w.w, acc.w);
  }
  float s1 = acc.x + acc.y + acc.z + acc.w;
  float s2 = acc.x*acc.x + acc.y*acc.y + acc.z*acc.z + acc.w*acc.w;
  #pragma unroll
  for (int m = 1; m < 64; m <<= 1) { s1 += __shfl_xor(s1, m); s2 += __shfl_xor(s2, m); }
  const int wid = t >> 6;
  if ((t & 63) == 0) { red[wid] = s1; red[wid + 4] = s2; }
  __syncthreads();
  s1 = red[0] + red[1] + red[2] + red[3];
  s2 = red[4] + red[5] + red[6] + red[7];
  float mu = s1 * (1.0f / 1024.0f);
  float var = s2 * (1.0f / 1024.0f) - mu * mu;
  float rstd = rsqrtf(var + 1e-5f);
  float4 g  = *(const float4*)&ln2g[d0];
  float4 bb = *(const float4*)&ln2b[d0];
  float4 o;
  o.x = (acc.x - mu) * rstd * g.x + bb.x;
  o.y = (acc.y - mu) * rstd * g.y + bb.y;
  o.z = (acc.z - mu) * rstd * g.z + bb.z;
  o.w = (acc.w - mu) * rstd * g.w + bb.w;
  *(float4*)&peb[(size_t)b * 1024 + d0] = o;
}

// ---------------------------------------------------------------------------
// K_FUSED v18: 512 blocks x 512 threads (8 waves), 64 rows per block.
// Hybrid phase A (round-16 win) + 8-wave blocks for 16 waves/CU:
//   x staged in LDS (XOR-swizzled); w1 DIRECT from global (L2).
//   8 K-groups x 64 thr; thread tile 8 rows x 8 cols; K=128/group; BK=16.
// Phase R: 4 passes of 16 rows through hacc[7][16][64].
// Phase B: 8 waves x 64 patterns; thread 8 rows x 8 pats (round-13 proven).
// launch_bounds(512,2): allocator free (the (.,4) variants forced 64 VGPR).
// LDS floats [15872] = 63.5 KB -> 2 blocks/CU iff VGPR <= 128.
//   A: xsT[8][16][68] [0..8704)
//   R: hacc[7][16][64] [8704..15872) | qns[64][68] [0..4352) overlay
//   B: qns stays | avm [4352..4864) avi [4864..5376) sidx [5376..5440)
// ---------------------------------------------------------------------------
__global__ __launch_bounds__(512, 2) void k_fused(
    const float* __restrict__ x, const float* __restrict__ w1,
    const float* __restrict__ b1, const float* __restrict__ ln1g,
    const float* __restrict__ ln1b, const float* __restrict__ knT,
    const float* __restrict__ invtp, const float* __restrict__ peb,
    float* __restrict__ outPe, float* __restrict__ outAs,
    float* __restrict__ outLg, float* __restrict__ outHi,
    float* __restrict__ outQ) {
  __shared__ float smem[15872];
  const int tid = threadIdx.x;
  const int rowbase = blockIdx.x * 64;

  // ---------------- phase A: GEMM1, 8 K-groups, BK=16, hybrid ----------
  const int g  = tid >> 6;          // 0..7
  const int t  = tid & 63;
  const int rt = t >> 3, ct = t & 7;
  const int r0 = rt * 8, c0 = ct * 8;
  const int kbase = g * 128;

  float* xsT = smem + g * 1088;     // [16][68]: k*68 + (row ^ sw(k))

  float acc[8][8];
  #pragma unroll
  for (int i = 0; i < 8; ++i)
    #pragma unroll
    for (int j = 0; j < 8; ++j) acc[i][j] = 0.f;

  const int srow = t >> 2;          // 0..15
  const int skc4 = (t & 3) * 4;     // 0,4,8,12
  const int ssw  = 8 * ((skc4 >> 3) & 1);
  const float* xp = x + (size_t)(rowbase + srow) * 1024 + kbase + skc4;

  for (int kt = 0; kt < 8; ++kt) {
    const int kb = kt * 16;
    float4 xv[4];
    #pragma unroll
    for (int p = 0; p < 4; ++p)
      xv[p] = ntl4(xp + (size_t)p * 16384 + kb);     // rows srow + 16p
    __syncthreads();
    #pragma unroll
    for (int p = 0; p < 4; ++p) {
      const int row = (srow + 16 * p) ^ ssw;
      xsT[(skc4+0)*68 + row] = xv[p].x;
      xsT[(skc4+1)*68 + row] = xv[p].y;
      xsT[(skc4+2)*68 + row] = xv[p].z;
      xsT[(skc4+3)*68 + row] = xv[p].w;
    }
    __syncthreads();
    #pragma unroll
    for (int kc = 0; kc < 4; ++kc) {               // chunks of 4 kk
      const float* wk = w1 + (size_t)(kbase + kb + kc * 4) * 64 + c0;
      float4 bv0 = *(const float4*)(wk);
      float4 bv1 = *(const float4*)(wk + 4);
      float4 bv2 = *(const float4*)(wk + 64);
      float4 bv3 = *(const float4*)(wk + 68);
      float4 bv4 = *(const float4*)(wk + 128);
      float4 bv5 = *(const float4*)(wk + 132);
      float4 bv6 = *(const float4*)(wk + 192);
      float4 bv7 = *(const float4*)(wk + 196);
#define CSTEP(D, BL, BH)                                                    \
      {                                                                     \
        const int kk = kc * 4 + D;                                          \
        const int rb = r0 ^ (8 * ((kk >> 3) & 1));                          \
        float4 a0 = *(float4*)&xsT[kk*68 + rb];                             \
        float4 a1 = *(float4*)&xsT[kk*68 + rb + 4];                         \
        float av[8] = {a0.x, a0.y, a0.z, a0.w, a1.x, a1.y, a1.z, a1.w};     \
        float bw[8] = {BL.x, BL.y, BL.z, BL.w, BH.x, BH.y, BH.z, BH.w};     \
        _Pragma("unroll")                                                   \
        for (int i = 0; i < 8; ++i)                                         \
          _Pragma("unroll")                                                 \
          for (int j = 0; j < 8; ++j)                                       \
            acc[i][j] = fmaf(av[i], bw[j], acc[i][j]);                      \
      }
      CSTEP(0, bv0, bv1) CSTEP(1, bv2, bv3) CSTEP(2, bv4, bv5) CSTEP(3, bv6, bv7)
#undef CSTEP
    }
  }

  // ---------------- phase R: 4 passes of 16 rows ----------------
  float* qns  = smem;               // [64][68] overlays xsT (dead)
  float* hacc = smem + 8704;        // [7][16][64]
  float bb[8], gg[8], ee[8];
  if (g == 0) {
    float4 t0 = *(const float4*)&b1[c0];
    float4 t1 = *(const float4*)&b1[c0 + 4];
    float4 t2 = *(const float4*)&ln1g[c0];
    float4 t3 = *(const float4*)&ln1g[c0 + 4];
    float4 t4 = *(const float4*)&ln1b[c0];
    float4 t5 = *(const float4*)&ln1b[c0 + 4];
    bb[0]=t0.x; bb[1]=t0.y; bb[2]=t0.z; bb[3]=t0.w; bb[4]=t1.x; bb[5]=t1.y; bb[6]=t1.z; bb[7]=t1.w;
    gg[0]=t2.x; gg[1]=t2.y; gg[2]=t2.z; gg[3]=t2.w; gg[4]=t3.x; gg[5]=t3.y; gg[6]=t3.z; gg[7]=t3.w;
    ee[0]=t4.x; ee[1]=t4.y; ee[2]=t4.z; ee[3]=t4.w; ee[4]=t5.x; ee[5]=t5.y; ee[6]=t5.z; ee[7]=t5.w;
  }
  #pragma unroll
  for (int p2 = 0; p2 < 4; ++p2) {
    __syncthreads();                // staging dead (p2=0) / prior pass done
    if (g > 0 && (rt >> 1) == p2) {
      float* hc = hacc + (g - 1) * 1024 + (r0 - 16 * p2) * 64 + c0;
      #pragma unroll
      for (int i = 0; i < 8; ++i) {
        float4 v0, v1;
        v0.x = acc[i][0]; v0.y = acc[i][1]; v0.z = acc[i][2]; v0.w = acc[i][3];
        v1.x = acc[i][4]; v1.y = acc[i][5]; v1.z = acc[i][6]; v1.w = acc[i][7];
        *(float4*)(hc + i * 64)     = v0;
        *(float4*)(hc + i * 64 + 4) = v1;
      }
    }
    __syncthreads();
    if (g == 0 && (rt >> 1) == p2) {
      #pragma unroll
      for (int i = 0; i < 8; ++i) {
        const int row = r0 + i;
        float h[8];
        #pragma unroll
        for (int j = 0; j < 8; ++j) h[j] = acc[i][j] + bb[j];
        #pragma unroll
        for (int g2 = 0; g2 < 7; ++g2) {
          float4 p0 = *(float4*)&hacc[g2*1024 + (row - 16*p2)*64 + c0];
          float4 p1 = *(float4*)&hacc[g2*1024 + (row - 16*p2)*64 + c0 + 4];
          h[0] += p0.x; h[1] += p0.y; h[2] += p0.z; h[3] += p0.w;
          h[4] += p1.x; h[5] += p1.y; h[6] += p1.z; h[7] += p1.w;
        }
        float s1 = 0.f, s2 = 0.f;
        #pragma unroll
        for (int j = 0; j < 8; ++j) { s1 += h[j]; s2 += h[j]*h[j]; }
        #pragma unroll
        for (int m = 1; m < 8; m <<= 1) { s1 += __shfl_xor(s1, m); s2 += __shfl_xor(s2, m); }
        const float mu   = s1 * 0.015625f;
        const float var  = s2 * 0.015625f - mu * mu;
        const float rstd = rsqrtf(var + 1e-5f);
        float q[8]; float t2s = 0.f;
        #pragma unroll
        for (int j = 0; j < 8; ++j) { q[j] = (h[j] - mu) * rstd * gg[j] + ee[j]; t2s += q[j]*q[j]; }
        #pragma unroll
        for (int m = 1; m < 8; m <<= 1) t2s += __shfl_xor(t2s, m);
        const float scl = 1.0f / fmaxf(sqrtf(t2s), 1e-12f);
        float4 qa, qc;
        qa.x = q[0]; qa.y = q[1]; qa.z = q[2]; qa.w = q[3];
        qc.x = q[4]; qc.y = q[5]; qc.z = q[6]; qc.w = q[7];
        nts4(&outQ[(size_t)(rowbase + row) * 64 + c0], qa);
        nts4(&outQ[(size_t)(rowbase + row) * 64 + c0 + 4], qc);
        #pragma unroll
        for (int j = 0; j < 8; ++j) qns[row*68 + c0 + j] = q[j] * scl;
      }
    }
  }
  __syncthreads();

  // ---------------- phase B: logits + argmax (Kn from global/L2) -----------
  const float invt = invtp[0];
  const int lane = tid & 63;
  const int w8   = tid >> 6;         // wave = 64-pattern chunk (8 waves)
  const int pt8  = lane >> 3;        // 0..7
  const int brt  = lane & 7;         // row mod 8
  const int pbase = w8 * 64 + pt8 * 8;

  float* avm = smem + 4352;          // [8][64]
  int*   avi = (int*)(smem + 4864);  // [8][64]
  int*   sidx = (int*)(smem + 5376); // [64]

  float a2[8][8];
  #pragma unroll
  for (int i = 0; i < 8; ++i)
    #pragma unroll
    for (int j = 0; j < 8; ++j) a2[i][j] = 0.f;

  for (int cb = 0; cb < 16; ++cb) {
    float kv[4][8];
    #pragma unroll
    for (int dc = 0; dc < 4; ++dc) {
      float4 k0 = *(const float4*)&knT[(size_t)(cb*4+dc)*512 + pbase];
      float4 k1 = *(const float4*)&knT[(size_t)(cb*4+dc)*512 + pbase + 4];
      kv[dc][0]=k0.x; kv[dc][1]=k0.y; kv[dc][2]=k0.z; kv[dc][3]=k0.w;
      kv[dc][4]=k1.x; kv[dc][5]=k1.y; kv[dc][6]=k1.z; kv[dc][7]=k1.w;
    }
    #pragma unroll
    for (int i = 0; i < 8; ++i) {
      float4 qv = *(float4*)&qns[(brt + 8*i)*68 + cb*4];
      float qq[4] = {qv.x, qv.y, qv.z, qv.w};
      #pragma unroll
      for (int dc = 0; dc < 4; ++dc)
        #pragma unroll
        for (int j = 0; j < 8; ++j)
          a2[i][j] = fmaf(qq[dc], kv[dc][j], a2[i][j]);
    }
  }

  #pragma unroll
  for (int i = 0; i < 8; ++i) {
    const int row = brt + 8*i;
    const size_t grow = (size_t)(rowbase + row);
    float v[8];
    float bm = -3.0e38f; int bi = 0;
    #pragma unroll
    for (int j = 0; j < 8; ++j) {
      v[j] = a2[i][j] * invt;
      if (v[j] > bm) { bm = v[j]; bi = pbase + j; }   // ascending j, first max
    }
    float4 o0, o1;
    o0.x = v[0]; o0.y = v[1]; o0.z = v[2]; o0.w = v[3];
    o1.x = v[4]; o1.y = v[5]; o1.z = v[6]; o1.w = v[7];
    nts4(&outLg[grow * 512 + pbase], o0);
    nts4(&outLg[grow * 512 + pbase + 4], o1);
    #pragma unroll
    for (int m = 8; m < 64; m <<= 1) {   // reduce over pt8 lanes (bits 3..5)
      float ov = __shfl_xor(bm, m);
      int   oi = __shfl_xor(bi, m);
      if (ov > bm || (ov == bm && oi < bi)) { bm = ov; bi = oi; }
    }
    if (pt8 == 0) { avm[w8*64 + row] = bm; avi[w8*64 + row] = bi; }
  }
  __syncthreads();

  if (tid < 64) {
    float bm = avm[tid]; int bi = avi[tid];
    #pragma unroll
    for (int w2 = 1; w2 < 8; ++w2) {
      float m = avm[w2*64 + tid];
      int   i = avi[w2*64 + tid];
      if (m > bm) { bm = m; bi = i; }   // ascending chunk, strict >
    }
    sidx[tid] = bi;
    __builtin_nontemporal_store((float)bi, &outHi[rowbase + tid]);
  }
  __syncthreads();

  // ---------------- one-hot assignments ----------------
  #pragma unroll
  for (int p = 0; p < 16; ++p) {
    const int id = tid + p * 512;
    const int r = id >> 7, c4 = (id & 127) * 4;
    const int b = sidx[r];
    float4 z; z.x = 0.f; z.y = 0.f; z.z = 0.f; z.w = 0.f;
    if (b >= c4 && b < c4 + 4) ((float*)&z)[b - c4] = 1.0f;
    nts4(&outAs[(size_t)(rowbase + r) * 512 + c4], z);
  }

  // ---------------- pattern_emb gather (PE table L2-hot) ----------------
  #pragma unroll 4
  for (int p = 0; p < 32; ++p) {
    const int id = tid + p * 512;
    const int r = id >> 8, c4 = id & 255;
    float4 pv = *(const float4*)&peb[((size_t)sidx[r] * 256 + c4) * 4];
    nts4(&outPe[((size_t)(rowbase + r) * 256 + c4) * 4], pv);
  }
}

// ---------------------------------------------------------------------------
extern "C" void kernel_launch(void* const* d_in, const int* in_sizes, int n_in,
                              void* d_out, int out_size, void* d_ws, size_t ws_size,
                              hipStream_t stream) {
  (void)in_sizes; (void)n_in; (void)out_size; (void)ws_size;
  const float* x        = (const float*)d_in[0];
  const float* w1       = (const float*)d_in[1];
  const float* b1       = (const float*)d_in[2];
  const float* ln1g     = (const float*)d_in[3];
  const float* ln1b     = (const float*)d_in[4];
  const float* patterns = (const float*)d_in[5];
  const float* w2       = (const float*)d_in[6];
  const float* b2       = (const float*)d_in[7];
  const float* ln2g     = (const float*)d_in[8];
  const float* ln2b     = (const float*)d_in[9];
  const int*   epoch    = (const int*)d_in[10];
  const int*   total    = (const int*)d_in[11];

  float* out = (float*)d_out;
  float* outPe = out + O_PE;
  float* outAs = out + O_AS;
  float* outLg = out + O_LG;
  float* outHi = out + O_HI;
  float* outQ  = out + O_Q;

  // workspace (bytes): [0..256) invt | [256..131328) knT [64][512]
  //                    [131328..2228480) PE fp32 [512][1024]
  float* wsf  = (float*)d_ws;
  float* invt = wsf;
  float* knT  = wsf + 64;
  float* peb  = (float*)((char*)d_ws + 131328);

  hipLaunchKernelGGL(k0_pre, dim3(512), dim3(256), 0, stream,
                     patterns, w2, b2, ln2g, ln2b, epoch, total, invt, knT, peb);
  hipLaunchKernelGGL(k_fused, dim3(512), dim3(512), 0, stream,
                     x, w1, b1, ln1g, ln1b, knT, invt, peb,
                     outPe, outAs, outLg, outHi, outQ);
}

// Round 19
// 157.772 us; speedup vs baseline: 1.2414x; 1.2414x over previous
//
#include <hip/hip_runtime.h>

// Problem constants (B=8, T=4096, D=1024, C=64, P=512)
// Outputs FLOAT32, concatenated: pattern_emb, assignments, logits, hard_indices, Q
#define O_PE 0
#define O_AS 33554432
#define O_LG 50331648
#define O_HI 67108864
#define O_Q  67141632

typedef float vf4 __attribute__((ext_vector_type(4)));  // native vector for NT builtins

__device__ __forceinline__ void nts4(float* p, float4 v) {
  vf4 t; t.x = v.x; t.y = v.y; t.z = v.z; t.w = v.w;
  __builtin_nontemporal_store(t, (vf4*)p);
}
__device__ __forceinline__ float4 ntl4(const float* p) {
  vf4 t = __builtin_nontemporal_load((const vf4*)p);
  float4 r; r.x = t.x; r.y = t.y; r.z = t.z; r.w = t.w;
  return r;
}

// ---------------------------------------------------------------------------
// K0: precompute  (grid = 512 blocks, one per pattern)
// ---------------------------------------------------------------------------
__global__ void k0_pre(const float* __restrict__ patterns, const float* __restrict__ w2,
                       const float* __restrict__ b2, const float* __restrict__ ln2g,
                       const float* __restrict__ ln2b, const int* __restrict__ epoch,
                       const int* __restrict__ total_epochs,
                       float* __restrict__ invt, float* __restrict__ knT,
                       float* __restrict__ peb) {
  const int b = blockIdx.x, t = threadIdx.x;
  __shared__ float pat[64];
  __shared__ float red[8];

  if (b == 0 && t == 0) {
    float ep = (float)epoch[0], te = (float)total_epochs[0];
    float warm = te * 0.1f;
    float temp;
    if (ep < warm) temp = 2.0f;
    else {
      float prog = (ep - warm) / (te - warm);
      temp = fmaxf(0.7f, 2.0f - 1.3f * prog);
    }
    invt[0] = 1.0f / temp;
  }

  if (t < 64) pat[t] = patterns[b * 64 + t];
  __syncthreads();

  if (t < 64) {
    float v = pat[t];
    float s = v * v;
    #pragma unroll
    for (int m = 1; m < 64; m <<= 1) s += __shfl_xor(s, m);
    float scale = 1.0f / fmaxf(sqrtf(s), 1e-12f);
    knT[(size_t)t * 512 + b] = v * scale;
  }

  const int d0 = t * 4;
  float4 acc = *(const float4*)&b2[d0];
  #pragma unroll 8
  for (int k = 0; k < 64; ++k) {
    float pk = pat[k];
    float4 w = *(const float4*)&w2[(size_t)k * 1024 + d0];
    acc.x = fmaf(pk, w.x, acc.x);
    acc.y = fmaf(pk, w.y, acc.y);
    acc.z = fmaf(pk, w.z, acc.z);
    acc.w = fmaf(pk, w.w, acc.w);
  }
  float s1 = acc.x + acc.y + acc.z + acc.w;
  float s2 = acc.x*acc.x + acc.y*acc.y + acc.z*acc.z + acc.w*acc.w;
  #pragma unroll
  for (int m = 1; m < 64; m <<= 1) { s1 += __shfl_xor(s1, m); s2 += __shfl_xor(s2, m); }
  const int wid = t >> 6;
  if ((t & 63) == 0) { red[wid] = s1; red[wid + 4] = s2; }
  __syncthreads();
  s1 = red[0] + red[1] + red[2] + red[3];
  s2 = red[4] + red[5] + red[6] + red[7];
  float mu = s1 * (1.0f / 1024.0f);
  float var = s2 * (1.0f / 1024.0f) - mu * mu;
  float rstd = rsqrtf(var + 1e-5f);
  float4 g  = *(const float4*)&ln2g[d0];
  float4 bb = *(const float4*)&ln2b[d0];
  float4 o;
  o.x = (acc.x - mu) * rstd * g.x + bb.x;
  o.y = (acc.y - mu) * rstd * g.y + bb.y;
  o.z = (acc.z - mu) * rstd * g.z + bb.z;
  o.w = (acc.w - mu) * rstd * g.w + bb.w;
  *(float4*)&peb[(size_t)b * 1024 + d0] = o;
}

// ---------------------------------------------------------------------------
// K_FUSED v19 (round-16 champion + x register prefetch):
// 512 blocks x 256 threads, 64 rows per block. Hybrid phase A:
//   x staged in LDS (XOR-swizzled), w1 DIRECT from global (L2).
//   NEW: kt+1's x-loads issue right after kt's LDS writes (xv 32 regs;
//   hybrid has no wv staging, so no round-11 spill mechanism).
// Phase R: cross-group reduce + LN + l2norm -> qns. Phase B: round-13/16.
// LDS floats [16640]: A: xsT[4][32][68] [0..8704)
//   R: hacc[3][64][64] [0..12288) overlay | qns [12288..16640)
//   B: avm [0..256) avi [256..512) sidx [512..576) overlay
// ---------------------------------------------------------------------------
__global__ __launch_bounds__(256, 2) void k_fused(
    const float* __restrict__ x, const float* __restrict__ w1,
    const float* __restrict__ b1, const float* __restrict__ ln1g,
    const float* __restrict__ ln1b, const float* __restrict__ knT,
    const float* __restrict__ invtp, const float* __restrict__ peb,
    float* __restrict__ outPe, float* __restrict__ outAs,
    float* __restrict__ outLg, float* __restrict__ outHi,
    float* __restrict__ outQ) {
  __shared__ float smem[16640];
  const int tid = threadIdx.x;
  const int rowbase = blockIdx.x * 64;

  // ---------------- phase A: GEMM1, 4 K-groups, BK=32, x-prefetch ---------
  const int g  = tid >> 6;
  const int t  = tid & 63;
  const int rt = t >> 3, ct = t & 7;
  const int r0 = rt * 8, c0 = ct * 8;
  const int kbase = g * 256;

  float* xsT = smem;                // g*2176 + k*68 + (row ^ sw(k))

  float acc[8][8];
  #pragma unroll
  for (int i = 0; i < 8; ++i)
    #pragma unroll
    for (int j = 0; j < 8; ++j) acc[i][j] = 0.f;

  const float* xp = x + (size_t)(rowbase + (t >> 3)) * 1024 + kbase + (t & 7) * 4;
  const int kc4 = (t & 7) * 4;
  const int sw  = 8 * ((kc4 >> 3) & 3);

  float4 xv[8];
  #pragma unroll
  for (int p = 0; p < 8; ++p)                       // prefetch kt = 0
    xv[p] = ntl4(xp + (size_t)p * 8192);

  for (int kt = 0; kt < 8; ++kt) {
    const int kb = kt * 32;
    __syncthreads();                                 // prior tile consumed
    #pragma unroll
    for (int p = 0; p < 8; ++p) {
      const int row = ((t >> 3) + 8 * p) ^ sw;
      xsT[g*2176 + (kc4+0)*68 + row] = xv[p].x;
      xsT[g*2176 + (kc4+1)*68 + row] = xv[p].y;
      xsT[g*2176 + (kc4+2)*68 + row] = xv[p].z;
      xsT[g*2176 + (kc4+3)*68 + row] = xv[p].w;
    }
    // issue NEXT tile's x loads now; they retire during this tile's FMAs
    if (kt < 7) {
      #pragma unroll
      for (int p = 0; p < 8; ++p)
        xv[p] = ntl4(xp + (size_t)p * 8192 + kb + 32);
    }
    __syncthreads();
    #pragma unroll 2
    for (int kc = 0; kc < 8; ++kc) {                 // chunks of 4 kk
      const float* wk = w1 + (size_t)(kbase + kb + kc * 4) * 64 + c0;
      float4 bv0 = *(const float4*)(wk);
      float4 bv1 = *(const float4*)(wk + 4);
      float4 bv2 = *(const float4*)(wk + 64);
      float4 bv3 = *(const float4*)(wk + 68);
      float4 bv4 = *(const float4*)(wk + 128);
      float4 bv5 = *(const float4*)(wk + 132);
      float4 bv6 = *(const float4*)(wk + 192);
      float4 bv7 = *(const float4*)(wk + 196);
#define CSTEP(D, BL, BH)                                                    \
      {                                                                     \
        const int kk = kc * 4 + D;                                          \
        const int rb = r0 ^ (8 * ((kk >> 3) & 3));                          \
        float4 a0 = *(float4*)&xsT[g*2176 + kk*68 + rb];                    \
        float4 a1 = *(float4*)&xsT[g*2176 + kk*68 + rb + 4];                \
        float av[8] = {a0.x, a0.y, a0.z, a0.w, a1.x, a1.y, a1.z, a1.w};     \
        float bw[8] = {BL.x, BL.y, BL.z, BL.w, BH.x, BH.y, BH.z, BH.w};     \
        _Pragma("unroll")                                                   \
        for (int i = 0; i < 8; ++i)                                         \
          _Pragma("unroll")                                                 \
          for (int j = 0; j < 8; ++j)                                       \
            acc[i][j] = fmaf(av[i], bw[j], acc[i][j]);                      \
      }
      CSTEP(0, bv0, bv1) CSTEP(1, bv2, bv3) CSTEP(2, bv4, bv5) CSTEP(3, bv6, bv7)
#undef CSTEP
    }
  }

  // ---------------- phase R: reduce + LN + l2norm ----------------
  __syncthreads();
  if (g > 0) {
    float* hc = smem + (g - 1) * 4096;
    #pragma unroll
    for (int i = 0; i < 8; ++i) {
      float4 v0, v1;
      v0.x = acc[i][0]; v0.y = acc[i][1]; v0.z = acc[i][2]; v0.w = acc[i][3];
      v1.x = acc[i][4]; v1.y = acc[i][5]; v1.z = acc[i][6]; v1.w = acc[i][7];
      *(float4*)&hc[(r0+i)*64 + c0]     = v0;
      *(float4*)&hc[(r0+i)*64 + c0 + 4] = v1;
    }
  }
  __syncthreads();
  float* qns = smem + 12288;        // [64][68]
  if (g == 0) {
    float bb[8], gg[8], ee[8];
    {
      float4 t0 = *(const float4*)&b1[c0];
      float4 t1 = *(const float4*)&b1[c0 + 4];
      float4 t2 = *(const float4*)&ln1g[c0];
      float4 t3 = *(const float4*)&ln1g[c0 + 4];
      float4 t4 = *(const float4*)&ln1b[c0];
      float4 t5 = *(const float4*)&ln1b[c0 + 4];
      bb[0]=t0.x; bb[1]=t0.y; bb[2]=t0.z; bb[3]=t0.w; bb[4]=t1.x; bb[5]=t1.y; bb[6]=t1.z; bb[7]=t1.w;
      gg[0]=t2.x; gg[1]=t2.y; gg[2]=t2.z; gg[3]=t2.w; gg[4]=t3.x; gg[5]=t3.y; gg[6]=t3.z; gg[7]=t3.w;
      ee[0]=t4.x; ee[1]=t4.y; ee[2]=t4.z; ee[3]=t4.w; ee[4]=t5.x; ee[5]=t5.y; ee[6]=t5.z; ee[7]=t5.w;
    }
    #pragma unroll
    for (int i = 0; i < 8; ++i) {
      const int row = r0 + i;
      float h[8];
      #pragma unroll
      for (int j = 0; j < 8; ++j) h[j] = acc[i][j] + bb[j];
      #pragma unroll
      for (int gg2 = 0; gg2 < 3; ++gg2) {
        float4 p0 = *(float4*)&smem[gg2*4096 + row*64 + c0];
        float4 p1 = *(float4*)&smem[gg2*4096 + row*64 + c0 + 4];
        h[0] += p0.x; h[1] += p0.y; h[2] += p0.z; h[3] += p0.w;
        h[4] += p1.x; h[5] += p1.y; h[6] += p1.z; h[7] += p1.w;
      }
      float s1 = 0.f, s2 = 0.f;
      #pragma unroll
      for (int j = 0; j < 8; ++j) { s1 += h[j]; s2 += h[j]*h[j]; }
      #pragma unroll
      for (int m = 1; m < 8; m <<= 1) { s1 += __shfl_xor(s1, m); s2 += __shfl_xor(s2, m); }
      const float mu   = s1 * 0.015625f;
      const float var  = s2 * 0.015625f - mu * mu;
      const float rstd = rsqrtf(var + 1e-5f);
      float q[8]; float t2s = 0.f;
      #pragma unroll
      for (int j = 0; j < 8; ++j) { q[j] = (h[j] - mu) * rstd * gg[j] + ee[j]; t2s += q[j]*q[j]; }
      #pragma unroll
      for (int m = 1; m < 8; m <<= 1) t2s += __shfl_xor(t2s, m);
      const float scl = 1.0f / fmaxf(sqrtf(t2s), 1e-12f);
      float4 qa, qc;
      qa.x = q[0]; qa.y = q[1]; qa.z = q[2]; qa.w = q[3];
      qc.x = q[4]; qc.y = q[5]; qc.z = q[6]; qc.w = q[7];
      nts4(&outQ[(size_t)(rowbase + row) * 64 + c0], qa);
      nts4(&outQ[(size_t)(rowbase + row) * 64 + c0 + 4], qc);
      #pragma unroll
      for (int j = 0; j < 8; ++j) qns[row*68 + c0 + j] = q[j] * scl;
    }
  }
  __syncthreads();

  // ---------------- phase B: logits + argmax (Kn from global/L2) -----------
  const float invt = invtp[0];
  const int lane = tid & 63;
  const int w    = tid >> 6;         // wave = 128-pattern chunk
  const int brt  = lane & 3;
  const int pt16 = lane >> 2;
  const int pbase = w * 128 + pt16 * 8;

  float* avm = smem;                 // [4][64]
  int*   avi = (int*)(smem + 256);   // [4][64]
  int*   sidx = (int*)(smem + 512);  // [64]

  float a2[16][8];
  #pragma unroll
  for (int i = 0; i < 16; ++i)
    #pragma unroll
    for (int j = 0; j < 8; ++j) a2[i][j] = 0.f;

  for (int cb = 0; cb < 16; ++cb) {
    float kv[4][8];
    #pragma unroll
    for (int dc = 0; dc < 4; ++dc) {
      float4 k0 = *(const float4*)&knT[(size_t)(cb*4+dc)*512 + pbase];
      float4 k1 = *(const float4*)&knT[(size_t)(cb*4+dc)*512 + pbase + 4];
      kv[dc][0]=k0.x; kv[dc][1]=k0.y; kv[dc][2]=k0.z; kv[dc][3]=k0.w;
      kv[dc][4]=k1.x; kv[dc][5]=k1.y; kv[dc][6]=k1.z; kv[dc][7]=k1.w;
    }
    #pragma unroll
    for (int i = 0; i < 16; ++i) {
      float4 qv = *(float4*)&qns[(brt + 4*i)*68 + cb*4];
      float qq[4] = {qv.x, qv.y, qv.z, qv.w};
      #pragma unroll
      for (int dc = 0; dc < 4; ++dc)
        #pragma unroll
        for (int j = 0; j < 8; ++j)
          a2[i][j] = fmaf(qq[dc], kv[dc][j], a2[i][j]);
    }
  }

  #pragma unroll
  for (int i = 0; i < 16; ++i) {
    const int row = brt + 4*i;
    const size_t grow = (size_t)(rowbase + row);
    float v[8];
    float bm = -3.0e38f; int bi = 0;
    #pragma unroll
    for (int j = 0; j < 8; ++j) {
      v[j] = a2[i][j] * invt;
      if (v[j] > bm) { bm = v[j]; bi = pbase + j; }   // ascending j, first max
    }
    float4 o0, o1;
    o0.x = v[0]; o0.y = v[1]; o0.z = v[2]; o0.w = v[3];
    o1.x = v[4]; o1.y = v[5]; o1.z = v[6]; o1.w = v[7];
    nts4(&outLg[grow * 512 + pbase], o0);
    nts4(&outLg[grow * 512 + pbase + 4], o1);
    #pragma unroll
    for (int m = 4; m < 64; m <<= 1) {
      float ov = __shfl_xor(bm, m);
      int   oi = __shfl_xor(bi, m);
      if (ov > bm || (ov == bm && oi < bi)) { bm = ov; bi = oi; }
    }
    if (pt16 == 0) { avm[w*64 + row] = bm; avi[w*64 + row] = bi; }
  }
  __syncthreads();

  if (tid < 64) {
    float bm = avm[tid]; int bi = avi[tid];
    #pragma unroll
    for (int w2 = 1; w2 < 4; ++w2) {
      float m = avm[w2*64 + tid];
      int   i = avi[w2*64 + tid];
      if (m > bm) { bm = m; bi = i; }   // ascending chunk, strict >
    }
    sidx[tid] = bi;
    __builtin_nontemporal_store((float)bi, &outHi[rowbase + tid]);
  }
  __syncthreads();

  // ---------------- one-hot assignments ----------------
  #pragma unroll
  for (int p = 0; p < 32; ++p) {
    const int id = tid + p * 256;
    const int r = id >> 7, c4 = (id & 127) * 4;
    const int b = sidx[r];
    float4 z; z.x = 0.f; z.y = 0.f; z.z = 0.f; z.w = 0.f;
    if (b >= c4 && b < c4 + 4) ((float*)&z)[b - c4] = 1.0f;
    nts4(&outAs[(size_t)(rowbase + r) * 512 + c4], z);
  }

  // ---------------- pattern_emb gather (PE table L2-hot) ----------------
  #pragma unroll 4
  for (int p = 0; p < 64; ++p) {
    const int id = tid + p * 256;
    const int r = id >> 8, c4 = id & 255;
    float4 pv = *(const float4*)&peb[((size_t)sidx[r] * 256 + c4) * 4];
    nts4(&outPe[((size_t)(rowbase + r) * 256 + c4) * 4], pv);
  }
}

// ---------------------------------------------------------------------------
extern "C" void kernel_launch(void* const* d_in, const int* in_sizes, int n_in,
                              void* d_out, int out_size, void* d_ws, size_t ws_size,
                              hipStream_t stream) {
  (void)in_sizes; (void)n_in; (void)out_size; (void)ws_size;
  const float* x        = (const float*)d_in[0];
  const float* w1       = (const float*)d_in[1];
  const float* b1       = (const float*)d_in[2];
  const float* ln1g     = (const float*)d_in[3];
  const float* ln1b     = (const float*)d_in[4];
  const float* patterns = (const float*)d_in[5];
  const float* w2       = (const float*)d_in[6];
  const float* b2       = (const float*)d_in[7];
  const float* ln2g     = (const float*)d_in[8];
  const float* ln2b     = (const float*)d_in[9];
  const int*   epoch    = (const int*)d_in[10];
  const int*   total    = (const int*)d_in[11];

  float* out = (float*)d_out;
  float* outPe = out + O_PE;
  float* outAs = out + O_AS;
  float* outLg = out + O_LG;
  float* outHi = out + O_HI;
  float* outQ  = out + O_Q;

  // workspace (bytes): [0..256) invt | [256..131328) knT [64][512]
  //                    [131328..2228480) PE fp32 [512][1024]
  float* wsf  = (float*)d_ws;
  float* invt = wsf;
  float* knT  = wsf + 64;
  float* peb  = (float*)((char*)d_ws + 131328);

  hipLaunchKernelGGL(k0_pre, dim3(512), dim3(256), 0, stream,
                     patterns, w2, b2, ln2g, ln2b, epoch, total, invt, knT, peb);
  hipLaunchKernelGGL(k_fused, dim3(512), dim3(256), 0, stream,
                     x, w1, b1, ln1g, ln1b, knT, invt, peb,
                     outPe, outAs, outLg, outHi, outQ);
}

// Round 20
// 138.453 us; speedup vs baseline: 1.4147x; 1.1395x over previous
//
#include <hip/hip_runtime.h>

// Problem constants (B=8, T=4096, D=1024, C=64, P=512)
// Outputs FLOAT32, concatenated: pattern_emb, assignments, logits, hard_indices, Q
#define O_PE 0
#define O_AS 33554432
#define O_LG 50331648
#define O_HI 67108864
#define O_Q  67141632

typedef float vf4 __attribute__((ext_vector_type(4)));  // native vector for NT builtins

__device__ __forceinline__ void nts4(float* p, float4 v) {
  vf4 t; t.x = v.x; t.y = v.y; t.z = v.z; t.w = v.w;
  __builtin_nontemporal_store(t, (vf4*)p);
}
__device__ __forceinline__ float4 ntl4(const float* p) {
  vf4 t = __builtin_nontemporal_load((const vf4*)p);
  float4 r; r.x = t.x; r.y = t.y; r.z = t.z; r.w = t.w;
  return r;
}

// ---------------------------------------------------------------------------
// K0: precompute  (grid = 512 blocks, one per pattern)
// ---------------------------------------------------------------------------
__global__ void k0_pre(const float* __restrict__ patterns, const float* __restrict__ w2,
                       const float* __restrict__ b2, const float* __restrict__ ln2g,
                       const float* __restrict__ ln2b, const int* __restrict__ epoch,
                       const int* __restrict__ total_epochs,
                       float* __restrict__ invt, float* __restrict__ knT,
                       float* __restrict__ peb) {
  const int b = blockIdx.x, t = threadIdx.x;
  __shared__ float pat[64];
  __shared__ float red[8];

  if (b == 0 && t == 0) {
    float ep = (float)epoch[0], te = (float)total_epochs[0];
    float warm = te * 0.1f;
    float temp;
    if (ep < warm) temp = 2.0f;
    else {
      float prog = (ep - warm) / (te - warm);
      temp = fmaxf(0.7f, 2.0f - 1.3f * prog);
    }
    invt[0] = 1.0f / temp;
  }

  if (t < 64) pat[t] = patterns[b * 64 + t];
  __syncthreads();

  if (t < 64) {
    float v = pat[t];
    float s = v * v;
    #pragma unroll
    for (int m = 1; m < 64; m <<= 1) s += __shfl_xor(s, m);
    float scale = 1.0f / fmaxf(sqrtf(s), 1e-12f);
    knT[(size_t)t * 512 + b] = v * scale;
  }

  const int d0 = t * 4;
  float4 acc = *(const float4*)&b2[d0];
  #pragma unroll 8
  for (int k = 0; k < 64; ++k) {
    float pk = pat[k];
    float4 w = *(const float4*)&w2[(size_t)k * 1024 + d0];
    acc.x = fmaf(pk, w.x, acc.x);
    acc.y = fmaf(pk, w.y, acc.y);
    acc.z = fmaf(pk, w.z, acc.z);
    acc.w = fmaf(pk, w.w, acc.w);
  }
  float s1 = acc.x + acc.y + acc.z + acc.w;
  float s2 = acc.x*acc.x + acc.y*acc.y + acc.z*acc.z + acc.w*acc.w;
  #pragma unroll
  for (int m = 1; m < 64; m <<= 1) { s1 += __shfl_xor(s1, m); s2 += __shfl_xor(s2, m); }
  const int wid = t >> 6;
  if ((t & 63) == 0) { red[wid] = s1; red[wid + 4] = s2; }
  __syncthreads();
  s1 = red[0] + red[1] + red[2] + red[3];
  s2 = red[4] + red[5] + red[6] + red[7];
  float mu = s1 * (1.0f / 1024.0f);
  float var = s2 * (1.0f / 1024.0f) - mu * mu;
  float rstd = rsqrtf(var + 1e-5f);
  float4 g  = *(const float4*)&ln2g[d0];
  float4 bb = *(const float4*)&ln2b[d0];
  float4 o;
  o.x = (acc.x - mu) * rstd * g.x + bb.x;
  o.y = (acc.y - mu) * rstd * g.y + bb.y;
  o.z = (acc.z - mu) * rstd * g.z + bb.z;
  o.w = (acc.w - mu) * rstd * g.w + bb.w;
  *(float4*)&peb[(size_t)b * 1024 + d0] = o;
}

// ---------------------------------------------------------------------------
// K_FUSED (round-16 champion, final): 512 blocks x 256 threads, 64 rows/block.
// Phase A: x staged in LDS (coalesced + broadcast reads, XOR-swizzled);
//   w1 read DIRECTLY from global (L2-resident 256 KB), 8 float4 per chunk.
//   Splits operand traffic across LDS and L2 pipes.
// Phase R: cross-group reduce + LN + l2norm -> qns.
// Phase B: logits (Kn from global/L2), argmax, Lg/Hi/As/PE. NT stores.
// LDS floats [16640]: A: xsT[4][32][68] [0..8704)
//   R: hacc[3][64][64] [0..12288) overlay | qns [12288..16640)
//   B: avm [0..256) avi [256..512) sidx [512..576) overlay
// ---------------------------------------------------------------------------
__global__ __launch_bounds__(256, 2) void k_fused(
    const float* __restrict__ x, const float* __restrict__ w1,
    const float* __restrict__ b1, const float* __restrict__ ln1g,
    const float* __restrict__ ln1b, const float* __restrict__ knT,
    const float* __restrict__ invtp, const float* __restrict__ peb,
    float* __restrict__ outPe, float* __restrict__ outAs,
    float* __restrict__ outLg, float* __restrict__ outHi,
    float* __restrict__ outQ) {
  __shared__ float smem[16640];
  const int tid = threadIdx.x;
  const int rowbase = blockIdx.x * 64;

  // ---------------- phase A: GEMM1, 4 K-groups, BK=32 ----------------
  const int g  = tid >> 6;
  const int t  = tid & 63;
  const int rt = t >> 3, ct = t & 7;
  const int r0 = rt * 8, c0 = ct * 8;
  const int kbase = g * 256;

  float* xsT = smem;                // g*2176 + k*68 + (row ^ sw(k))

  float acc[8][8];
  #pragma unroll
  for (int i = 0; i < 8; ++i)
    #pragma unroll
    for (int j = 0; j < 8; ++j) acc[i][j] = 0.f;

  const float* xp = x + (size_t)(rowbase + (t >> 3)) * 1024 + kbase + (t & 7) * 4;

  for (int kt = 0; kt < 8; ++kt) {
    const int kb = kt * 32;
    float4 xv[8];
    #pragma unroll
    for (int p = 0; p < 8; ++p)
      xv[p] = ntl4(xp + (size_t)p * 8192 + kb);
    __syncthreads();
    {
      const int kc4 = (t & 7) * 4;
      const int sw = 8 * ((kc4 >> 3) & 3);      // same for kc4..kc4+3
      #pragma unroll
      for (int p = 0; p < 8; ++p) {
        const int row = ((t >> 3) + 8 * p) ^ sw;
        xsT[g*2176 + (kc4+0)*68 + row] = xv[p].x;
        xsT[g*2176 + (kc4+1)*68 + row] = xv[p].y;
        xsT[g*2176 + (kc4+2)*68 + row] = xv[p].z;
        xsT[g*2176 + (kc4+3)*68 + row] = xv[p].w;
      }
    }
    __syncthreads();
    #pragma unroll 2
    for (int kc = 0; kc < 8; ++kc) {           // chunks of 4 kk
      const float* wk = w1 + (size_t)(kbase + kb + kc * 4) * 64 + c0;
      float4 bv0 = *(const float4*)(wk);
      float4 bv1 = *(const float4*)(wk + 4);
      float4 bv2 = *(const float4*)(wk + 64);
      float4 bv3 = *(const float4*)(wk + 68);
      float4 bv4 = *(const float4*)(wk + 128);
      float4 bv5 = *(const float4*)(wk + 132);
      float4 bv6 = *(const float4*)(wk + 192);
      float4 bv7 = *(const float4*)(wk + 196);
#define CSTEP(D, BL, BH)                                                    \
      {                                                                     \
        const int kk = kc * 4 + D;                                          \
        const int rb = r0 ^ (8 * ((kk >> 3) & 3));                          \
        float4 a0 = *(float4*)&xsT[g*2176 + kk*68 + rb];                    \
        float4 a1 = *(float4*)&xsT[g*2176 + kk*68 + rb + 4];                \
        float av[8] = {a0.x, a0.y, a0.z, a0.w, a1.x, a1.y, a1.z, a1.w};     \
        float bw[8] = {BL.x, BL.y, BL.z, BL.w, BH.x, BH.y, BH.z, BH.w};     \
        _Pragma("unroll")                                                   \
        for (int i = 0; i < 8; ++i)                                         \
          _Pragma("unroll")                                                 \
          for (int j = 0; j < 8; ++j)                                       \
            acc[i][j] = fmaf(av[i], bw[j], acc[i][j]);                      \
      }
      CSTEP(0, bv0, bv1) CSTEP(1, bv2, bv3) CSTEP(2, bv4, bv5) CSTEP(3, bv6, bv7)
#undef CSTEP
    }
  }

  // ---------------- phase R: reduce + LN + l2norm ----------------
  __syncthreads();
  if (g > 0) {
    float* hc = smem + (g - 1) * 4096;
    #pragma unroll
    for (int i = 0; i < 8; ++i) {
      float4 v0, v1;
      v0.x = acc[i][0]; v0.y = acc[i][1]; v0.z = acc[i][2]; v0.w = acc[i][3];
      v1.x = acc[i][4]; v1.y = acc[i][5]; v1.z = acc[i][6]; v1.w = acc[i][7];
      *(float4*)&hc[(r0+i)*64 + c0]     = v0;
      *(float4*)&hc[(r0+i)*64 + c0 + 4] = v1;
    }
  }
  __syncthreads();
  float* qns = smem + 12288;        // [64][68]
  if (g == 0) {
    float bb[8], gg[8], ee[8];
    {
      float4 t0 = *(const float4*)&b1[c0];
      float4 t1 = *(const float4*)&b1[c0 + 4];
      float4 t2 = *(const float4*)&ln1g[c0];
      float4 t3 = *(const float4*)&ln1g[c0 + 4];
      float4 t4 = *(const float4*)&ln1b[c0];
      float4 t5 = *(const float4*)&ln1b[c0 + 4];
      bb[0]=t0.x; bb[1]=t0.y; bb[2]=t0.z; bb[3]=t0.w; bb[4]=t1.x; bb[5]=t1.y; bb[6]=t1.z; bb[7]=t1.w;
      gg[0]=t2.x; gg[1]=t2.y; gg[2]=t2.z; gg[3]=t2.w; gg[4]=t3.x; gg[5]=t3.y; gg[6]=t3.z; gg[7]=t3.w;
      ee[0]=t4.x; ee[1]=t4.y; ee[2]=t4.z; ee[3]=t4.w; ee[4]=t5.x; ee[5]=t5.y; ee[6]=t5.z; ee[7]=t5.w;
    }
    #pragma unroll
    for (int i = 0; i < 8; ++i) {
      const int row = r0 + i;
      float h[8];
      #pragma unroll
      for (int j = 0; j < 8; ++j) h[j] = acc[i][j] + bb[j];
      #pragma unroll
      for (int gg2 = 0; gg2 < 3; ++gg2) {
        float4 p0 = *(float4*)&smem[gg2*4096 + row*64 + c0];
        float4 p1 = *(float4*)&smem[gg2*4096 + row*64 + c0 + 4];
        h[0] += p0.x; h[1] += p0.y; h[2] += p0.z; h[3] += p0.w;
        h[4] += p1.x; h[5] += p1.y; h[6] += p1.z; h[7] += p1.w;
      }
      float s1 = 0.f, s2 = 0.f;
      #pragma unroll
      for (int j = 0; j < 8; ++j) { s1 += h[j]; s2 += h[j]*h[j]; }
      #pragma unroll
      for (int m = 1; m < 8; m <<= 1) { s1 += __shfl_xor(s1, m); s2 += __shfl_xor(s2, m); }
      const float mu   = s1 * 0.015625f;
      const float var  = s2 * 0.015625f - mu * mu;
      const float rstd = rsqrtf(var + 1e-5f);
      float q[8]; float t2s = 0.f;
      #pragma unroll
      for (int j = 0; j < 8; ++j) { q[j] = (h[j] - mu) * rstd * gg[j] + ee[j]; t2s += q[j]*q[j]; }
      #pragma unroll
      for (int m = 1; m < 8; m <<= 1) t2s += __shfl_xor(t2s, m);
      const float scl = 1.0f / fmaxf(sqrtf(t2s), 1e-12f);
      float4 qa, qc;
      qa.x = q[0]; qa.y = q[1]; qa.z = q[2]; qa.w = q[3];
      qc.x = q[4]; qc.y = q[5]; qc.z = q[6]; qc.w = q[7];
      nts4(&outQ[(size_t)(rowbase + row) * 64 + c0], qa);
      nts4(&outQ[(size_t)(rowbase + row) * 64 + c0 + 4], qc);
      #pragma unroll
      for (int j = 0; j < 8; ++j) qns[row*68 + c0 + j] = q[j] * scl;
    }
  }
  __syncthreads();

  // ---------------- phase B: logits + argmax (Kn from global/L2) -----------
  const float invt = invtp[0];
  const int lane = tid & 63;
  const int w    = tid >> 6;         // wave = 128-pattern chunk
  const int brt  = lane & 3;
  const int pt16 = lane >> 2;
  const int pbase = w * 128 + pt16 * 8;

  float* avm = smem;                 // [4][64]
  int*   avi = (int*)(smem + 256);   // [4][64]
  int*   sidx = (int*)(smem + 512);  // [64]

  float a2[16][8];
  #pragma unroll
  for (int i = 0; i < 16; ++i)
    #pragma unroll
    for (int j = 0; j < 8; ++j) a2[i][j] = 0.f;

  for (int cb = 0; cb < 16; ++cb) {
    float kv[4][8];
    #pragma unroll
    for (int dc = 0; dc < 4; ++dc) {
      float4 k0 = *(const float4*)&knT[(size_t)(cb*4+dc)*512 + pbase];
      float4 k1 = *(const float4*)&knT[(size_t)(cb*4+dc)*512 + pbase + 4];
      kv[dc][0]=k0.x; kv[dc][1]=k0.y; kv[dc][2]=k0.z; kv[dc][3]=k0.w;
      kv[dc][4]=k1.x; kv[dc][5]=k1.y; kv[dc][6]=k1.z; kv[dc][7]=k1.w;
    }
    #pragma unroll
    for (int i = 0; i < 16; ++i) {
      float4 qv = *(float4*)&qns[(brt + 4*i)*68 + cb*4];
      float qq[4] = {qv.x, qv.y, qv.z, qv.w};
      #pragma unroll
      for (int dc = 0; dc < 4; ++dc)
        #pragma unroll
        for (int j = 0; j < 8; ++j)
          a2[i][j] = fmaf(qq[dc], kv[dc][j], a2[i][j]);
    }
  }

  #pragma unroll
  for (int i = 0; i < 16; ++i) {
    const int row = brt + 4*i;
    const size_t grow = (size_t)(rowbase + row);
    float v[8];
    float bm = -3.0e38f; int bi = 0;
    #pragma unroll
    for (int j = 0; j < 8; ++j) {
      v[j] = a2[i][j] * invt;
      if (v[j] > bm) { bm = v[j]; bi = pbase + j; }   // ascending j, first max
    }
    float4 o0, o1;
    o0.x = v[0]; o0.y = v[1]; o0.z = v[2]; o0.w = v[3];
    o1.x = v[4]; o1.y = v[5]; o1.z = v[6]; o1.w = v[7];
    nts4(&outLg[grow * 512 + pbase], o0);
    nts4(&outLg[grow * 512 + pbase + 4], o1);
    #pragma unroll
    for (int m = 4; m < 64; m <<= 1) {
      float ov = __shfl_xor(bm, m);
      int   oi = __shfl_xor(bi, m);
      if (ov > bm || (ov == bm && oi < bi)) { bm = ov; bi = oi; }
    }
    if (pt16 == 0) { avm[w*64 + row] = bm; avi[w*64 + row] = bi; }
  }
  __syncthreads();

  if (tid < 64) {
    float bm = avm[tid]; int bi = avi[tid];
    #pragma unroll
    for (int w2 = 1; w2 < 4; ++w2) {
      float m = avm[w2*64 + tid];
      int   i = avi[w2*64 + tid];
      if (m > bm) { bm = m; bi = i; }   // ascending chunk, strict >
    }
    sidx[tid] = bi;
    __builtin_nontemporal_store((float)bi, &outHi[rowbase + tid]);
  }
  __syncthreads();

  // ---------------- one-hot assignments ----------------
  #pragma unroll
  for (int p = 0; p < 32; ++p) {
    const int id = tid + p * 256;
    const int r = id >> 7, c4 = (id & 127) * 4;
    const int b = sidx[r];
    float4 z; z.x = 0.f; z.y = 0.f; z.z = 0.f; z.w = 0.f;
    if (b >= c4 && b < c4 + 4) ((float*)&z)[b - c4] = 1.0f;
    nts4(&outAs[(size_t)(rowbase + r) * 512 + c4], z);
  }

  // ---------------- pattern_emb gather (PE table L2-hot) ----------------
  #pragma unroll 4
  for (int p = 0; p < 64; ++p) {
    const int id = tid + p * 256;
    const int r = id >> 8, c4 = id & 255;
    float4 pv = *(const float4*)&peb[((size_t)sidx[r] * 256 + c4) * 4];
    nts4(&outPe[((size_t)(rowbase + r) * 256 + c4) * 4], pv);
  }
}

// ---------------------------------------------------------------------------
extern "C" void kernel_launch(void* const* d_in, const int* in_sizes, int n_in,
                              void* d_out, int out_size, void* d_ws, size_t ws_size,
                              hipStream_t stream) {
  (void)in_sizes; (void)n_in; (void)out_size; (void)ws_size;
  const float* x        = (const float*)d_in[0];
  const float* w1       = (const float*)d_in[1];
  const float* b1       = (const float*)d_in[2];
  const float* ln1g     = (const float*)d_in[3];
  const float* ln1b     = (const float*)d_in[4];
  const float* patterns = (const float*)d_in[5];
  const float* w2       = (const float*)d_in[6];
  const float* b2       = (const float*)d_in[7];
  const float* ln2g     = (const float*)d_in[8];
  const float* ln2b     = (const float*)d_in[9];
  const int*   epoch    = (const int*)d_in[10];
  const int*   total    = (const int*)d_in[11];

  float* out = (float*)d_out;
  float* outPe = out + O_PE;
  float* outAs = out + O_AS;
  float* outLg = out + O_LG;
  float* outHi = out + O_HI;
  float* outQ  = out + O_Q;

  // workspace (bytes): [0..256) invt | [256..131328) knT [64][512]
  //                    [131328..2228480) PE fp32 [512][1024]
  float* wsf  = (float*)d_ws;
  float* invt = wsf;
  float* knT  = wsf + 64;
  float* peb  = (float*)((char*)d_ws + 131328);

  hipLaunchKernelGGL(k0_pre, dim3(512), dim3(256), 0, stream,
                     patterns, w2, b2, ln2g, ln2b, epoch, total, invt, knT, peb);
  hipLaunchKernelGGL(k_fused, dim3(512), dim3(256), 0, stream,
                     x, w1, b1, ln1g, ln1b, knT, invt, peb,
                     outPe, outAs, outLg, outHi, outQ);
}